// Round 1
// baseline (556.985 us; speedup 1.0000x reference)
//
#include <hip/hip_runtime.h>
#include <hip/hip_bf16.h>
#include <cstdint>
#include <cstddef>

#define NI 15
#define NL 16
#define DD 1024
#define NC 100
#define HH 256
#define BB 4096

typedef __attribute__((ext_vector_type(8))) short bf16x8;
typedef __attribute__((ext_vector_type(8))) unsigned short u16x8;
typedef __attribute__((ext_vector_type(4))) float f32x4;

__device__ __forceinline__ unsigned short f2bf(float f) {
  union { float f; unsigned u; } v; v.f = f;
  return (unsigned short)((v.u + 0x7FFFu + ((v.u >> 16) & 1u)) >> 16);
}

// async global->LDS, 16B per lane; LDS dest is wave-uniform base + lane*16
__device__ __forceinline__ void gld_lds16(const void* g, void* s) {
  __builtin_amdgcn_global_load_lds(
      (const __attribute__((address_space(1))) unsigned int*)g,
      (__attribute__((address_space(3))) unsigned int*)s, 16, 0, 0);
}

// ---------------- fp32 -> bf16 convert ----------------
__global__ __launch_bounds__(256) void k_convert(const float* __restrict__ src,
                                                 unsigned short* __restrict__ dst,
                                                 int n) {
  const int stride = gridDim.x * blockDim.x * 4;
  for (int i = (blockIdx.x * blockDim.x + threadIdx.x) * 4; i < n; i += stride) {
    float4 v = *reinterpret_cast<const float4*>(src + i);
    ushort4 o;
    o.x = f2bf(v.x); o.y = f2bf(v.y); o.z = f2bf(v.z); o.w = f2bf(v.w);
    *reinterpret_cast<ushort4*>(dst + i) = o;
  }
}

// ---------------- gumbel-softmax gating: split_prob[15][4096] ----------------
// block = one batch row b (4 waves); each wave handles nodes n = w, w+4, w+8, w+12
__global__ __launch_bounds__(256) void k_gate(
    const float* __restrict__ x, const float* __restrict__ gu,
    const float* __restrict__ fl, const float* __restrict__ thr,
    const float* __restrict__ fw, float* __restrict__ split) {
  const int b = blockIdx.x;
  const int w = threadIdx.x >> 6, lane = threadIdx.x & 63;
  const int d0 = lane * 16;

  float xr[16];
  {
    const float* xp = x + (size_t)b * DD + d0;
    for (int j = 0; j < 4; ++j) {
      float4 v = *reinterpret_cast<const float4*>(xp + j * 4);
      xr[j * 4 + 0] = v.x; xr[j * 4 + 1] = v.y;
      xr[j * 4 + 2] = v.z; xr[j * 4 + 3] = v.w;
    }
  }

  for (int n = w; n < NI; n += 4) {
    const float* gp = gu + ((size_t)n * BB + b) * DD + d0;
    const float* fp = fl + (size_t)n * DD + d0;
    const float* wp = fw + (size_t)n * DD + d0;
    float num = 0.f, den = 0.f;
    for (int j = 0; j < 4; ++j) {
      float4 g4 = *reinterpret_cast<const float4*>(gp + j * 4);
      float4 f4 = *reinterpret_cast<const float4*>(fp + j * 4);
      float4 w4 = *reinterpret_cast<const float4*>(wp + j * 4);
      float gv[4] = {g4.x, g4.y, g4.z, g4.w};
      float fv[4] = {f4.x, f4.y, f4.z, f4.w};
      float wv[4] = {w4.x, w4.y, w4.z, w4.w};
      for (int q = 0; q < 4; ++q) {
        float gg = -__logf(-__logf(gv[q] + 1e-10f) + 1e-10f);  // gumbel noise
        float e = __expf(fv[q] + gg);                          // tau = 1
        den += e;
        num += xr[j * 4 + q] * wv[q] * e;
      }
    }
    for (int off = 32; off; off >>= 1) {
      num += __shfl_xor(num, off);
      den += __shfl_xor(den, off);
    }
    if (lane == 0) {
      float agg = num / den;
      split[n * BB + b] = 1.f / (1.f + __expf(-(agg - thr[n])));
    }
  }
}

// ---------------- leaf routing probs: lp[4096][16] ----------------
__global__ __launch_bounds__(256) void k_leaf(const float* __restrict__ split,
                                              float* __restrict__ lp) {
  const int b = blockIdx.x * blockDim.x + threadIdx.x;
  if (b >= BB) return;
  float s[NI];
  for (int i = 0; i < NI; ++i) s[i] = split[i * BB + b];
  for (int leaf = 0; leaf < NL; ++leaf) {
    float p = 1.f;
    int node = 0;
    for (int lev = 0; lev < 4; ++lev) {
      int bit = (leaf >> (3 - lev)) & 1;
      p *= bit ? s[node] : (1.f - s[node]);
      node = 2 * node + 1 + bit;
    }
    lp[(size_t)b * NL + leaf] = p;
  }
}

// ---------------- GEMM1: Hs[l][b][h] = lp[b][l] * relu(x@W1[l]^T + b1[l]) in bf16
// 128x128 tile, BK=64, 4 waves (2x2 of 64x64), 16x16x32 bf16 MFMA (m97 structure)
__global__ __launch_bounds__(256) void k_gemm1(
    const unsigned short* __restrict__ xb, const unsigned short* __restrict__ w1b,
    const float* __restrict__ b1, const float* __restrict__ lp,
    unsigned short* __restrict__ hs) {
  __shared__ unsigned short lA[128 * 64];
  __shared__ unsigned short lB[128 * 64];
  __shared__ float s_lp[128];
  __shared__ float s_b1[128];

  const int tid = threadIdx.x;
  const int mt = blockIdx.x, nt = blockIdx.y, l = blockIdx.z;
  const int m0 = mt * 128, n0 = nt * 128;

  if (tid < 128) s_lp[tid] = lp[(size_t)(m0 + tid) * NL + l];
  else           s_b1[tid - 128] = b1[l * HH + n0 + (tid - 128)];

  const unsigned short* Ag = xb + (size_t)m0 * DD;
  const unsigned short* Bg = w1b + (size_t)l * HH * DD + (size_t)n0 * DD;

  f32x4 acc[4][4] = {};
  const int wv = tid >> 6, lane = tid & 63;
  const int wm = (wv & 1) * 64, wn = (wv >> 1) * 64;
  const int fr = lane & 15, fk = (lane >> 4) * 8;
  const int srow = tid >> 3, scol = (tid & 7) * 8;

  for (int k0 = 0; k0 < DD; k0 += 64) {
    for (int i = 0; i < 4; ++i)
      gld_lds16(Ag + (size_t)(srow + i * 32) * DD + k0 + scol,
                &lA[(srow + i * 32) * 64 + scol]);
    for (int i = 0; i < 4; ++i)
      gld_lds16(Bg + (size_t)(srow + i * 32) * DD + k0 + scol,
                &lB[(srow + i * 32) * 64 + scol]);
    __syncthreads();  // drains vmcnt (compiler emits s_waitcnt before s_barrier)
    for (int kk = 0; kk < 64; kk += 32) {
      bf16x8 av[4], bv[4];
      for (int i = 0; i < 4; ++i)
        av[i] = *reinterpret_cast<const bf16x8*>(&lA[(wm + i * 16 + fr) * 64 + kk + fk]);
      for (int i = 0; i < 4; ++i)
        bv[i] = *reinterpret_cast<const bf16x8*>(&lB[(wn + i * 16 + fr) * 64 + kk + fk]);
      for (int mi = 0; mi < 4; ++mi)
        for (int ni = 0; ni < 4; ++ni)
          acc[mi][ni] = __builtin_amdgcn_mfma_f32_16x16x32_bf16(av[mi], bv[ni], acc[mi][ni], 0, 0, 0);
    }
    __syncthreads();
  }

  // C/D layout (m89-verified): col = lane&15, row = (lane>>4)*4 + reg
  const int cr = (lane >> 4) * 4, cc = lane & 15;
  for (int mi = 0; mi < 4; ++mi)
    for (int ni = 0; ni < 4; ++ni) {
      const int col = wn + ni * 16 + cc;
      const float bias = s_b1[col];
      for (int j = 0; j < 4; ++j) {
        const int row = wm + mi * 16 + cr + j;
        float v = acc[mi][ni][j] + bias;
        v = fmaxf(v, 0.f) * s_lp[row];
        hs[(size_t)l * BB * HH + (size_t)(m0 + row) * HH + (n0 + col)] = f2bf(v);
      }
    }
}

// ---------------- GEMM2 + combine: out[b][c] = sum_{l,h} Hs[l][b][h]*W2[l][c][h] + sum_l lp*b2
// M-tile 128, N=128 (100 real), split-K over 8 chunks of 512, fp32 atomics into zeroed out
__global__ __launch_bounds__(256) void k_gemm2(
    const unsigned short* __restrict__ hs, const unsigned short* __restrict__ w2b,
    const float* __restrict__ b2, const float* __restrict__ lp,
    float* __restrict__ out) {
  __shared__ unsigned short lA[128 * 64];
  __shared__ unsigned short lB[128 * 64];
  __shared__ float s_lp[128 * NL];

  const int tid = threadIdx.x;
  const int mt = blockIdx.x, kc = blockIdx.y;
  const int m0 = mt * 128;

  {  // stage lp tile [128][16]
    const float4* src = reinterpret_cast<const float4*>(lp + (size_t)m0 * NL);
    reinterpret_cast<float4*>(s_lp)[tid * 2 + 0] = src[tid * 2 + 0];
    reinterpret_cast<float4*>(s_lp)[tid * 2 + 1] = src[tid * 2 + 1];
  }

  f32x4 acc[4][4] = {};
  const int wv = tid >> 6, lane = tid & 63;
  const int wm = (wv & 1) * 64, wn = (wv >> 1) * 64;
  const int fr = lane & 15, fk = (lane >> 4) * 8;
  const int srow = tid >> 3, scol = (tid & 7) * 8;

  for (int ks = 0; ks < 8; ++ks) {
    const int kg = kc * 512 + ks * 64;
    const int l = kg >> 8, h0 = kg & 255;  // BK=64 divides 256: one leaf per step
    const unsigned short* Ag = hs + (size_t)l * BB * HH + (size_t)m0 * HH + h0;
    for (int i = 0; i < 4; ++i)
      gld_lds16(Ag + (size_t)(srow + i * 32) * HH + scol,
                &lA[(srow + i * 32) * 64 + scol]);
    const unsigned short* Bg = w2b + (size_t)l * NC * HH + h0;
    for (int i = 0; i < 4; ++i) {
      const int c = srow + i * 32;
      u16x8 v = {};
      if (c < NC) v = *reinterpret_cast<const u16x8*>(Bg + (size_t)c * HH + scol);
      *reinterpret_cast<u16x8*>(&lB[c * 64 + scol]) = v;
    }
    __syncthreads();
    for (int kk = 0; kk < 64; kk += 32) {
      bf16x8 av[4], bv[4];
      for (int i = 0; i < 4; ++i)
        av[i] = *reinterpret_cast<const bf16x8*>(&lA[(wm + i * 16 + fr) * 64 + kk + fk]);
      for (int i = 0; i < 4; ++i)
        bv[i] = *reinterpret_cast<const bf16x8*>(&lB[(wn + i * 16 + fr) * 64 + kk + fk]);
      for (int mi = 0; mi < 4; ++mi)
        for (int ni = 0; ni < 4; ++ni)
          acc[mi][ni] = __builtin_amdgcn_mfma_f32_16x16x32_bf16(av[mi], bv[ni], acc[mi][ni], 0, 0, 0);
    }
    __syncthreads();
  }

  const int cr = (lane >> 4) * 4, cc = lane & 15;
  for (int mi = 0; mi < 4; ++mi)
    for (int ni = 0; ni < 4; ++ni) {
      const int col = wn + ni * 16 + cc;
      if (col < NC) {
        for (int j = 0; j < 4; ++j) {
          const int row = wm + mi * 16 + cr + j;
          float v = acc[mi][ni][j];
          if (kc == 0) {  // fold bias term sum_l lp[b][l]*b2[l][c] once
            float bias = 0.f;
            for (int q = 0; q < NL; ++q) bias += s_lp[row * NL + q] * b2[q * NC + col];
            v += bias;
          }
          atomicAdd(&out[(size_t)(m0 + row) * NC + col], v);
        }
      }
    }
}

// ---------------- launch ----------------
extern "C" void kernel_launch(void* const* d_in, const int* in_sizes, int n_in,
                              void* d_out, int out_size, void* d_ws, size_t ws_size,
                              hipStream_t stream) {
  const float* x   = (const float*)d_in[0];
  const float* gu  = (const float*)d_in[1];
  const float* fl  = (const float*)d_in[2];
  const float* thr = (const float*)d_in[3];
  const float* fw  = (const float*)d_in[4];
  const float* W1  = (const float*)d_in[5];
  const float* b1  = (const float*)d_in[6];
  const float* W2  = (const float*)d_in[7];
  const float* b2  = (const float*)d_in[8];
  float* out = (float*)d_out;

  char* ws = (char*)d_ws;
  // ws layout (bytes): total ~51.7 MB
  float* split          = (float*)(ws + 0);                 // 15*4096*4      = 245760
  float* lp             = (float*)(ws + 245760);            // 4096*16*4      = 262144
  unsigned short* xb    = (unsigned short*)(ws + 507904);   // 4096*1024*2    = 8388608
  unsigned short* w1b   = (unsigned short*)(ws + 8896512);  // 16*256*1024*2  = 8388608
  unsigned short* w2b   = (unsigned short*)(ws + 17285120); // 16*100*256*2   = 819200
  unsigned short* hsb   = (unsigned short*)(ws + 18104320); // 16*4096*256*2  = 33554432

  k_convert<<<2048, 256, 0, stream>>>(x,  xb,  BB * DD);
  k_convert<<<2048, 256, 0, stream>>>(W1, w1b, NL * HH * DD);
  k_convert<<<512,  256, 0, stream>>>(W2, w2b, NL * NC * HH);

  k_gate<<<BB, 256, 0, stream>>>(x, gu, fl, thr, fw, split);
  k_leaf<<<16, 256, 0, stream>>>(split, lp);

  k_gemm1<<<dim3(32, 2, 16), 256, 0, stream>>>(xb, w1b, b1, lp, hsb);

  hipMemsetAsync(out, 0, (size_t)out_size * sizeof(float), stream);
  k_gemm2<<<dim3(32, 8, 1), 256, 0, stream>>>(hsb, w2b, b2, lp, out);
}

// Round 2
// 472.460 us; speedup vs baseline: 1.1789x; 1.1789x over previous
//
#include <hip/hip_runtime.h>
#include <hip/hip_bf16.h>
#include <cstdint>
#include <cstddef>

#define NI 15
#define NL 16
#define DD 1024
#define NC 100
#define HH 256
#define BB 4096

typedef __attribute__((ext_vector_type(8))) short bf16x8;
typedef __attribute__((ext_vector_type(8))) unsigned short u16x8;
typedef __attribute__((ext_vector_type(4))) float f32x4;

__device__ __forceinline__ unsigned short f2bf(float f) {
  union { float f; unsigned u; } v; v.f = f;
  return (unsigned short)((v.u + 0x7FFFu + ((v.u >> 16) & 1u)) >> 16);
}

// async global->LDS, 16B per lane; LDS dest is wave-uniform base + lane*16
__device__ __forceinline__ void gld_lds16(const void* g, void* s) {
  __builtin_amdgcn_global_load_lds(
      (const __attribute__((address_space(1))) unsigned int*)g,
      (__attribute__((address_space(3))) unsigned int*)s, 16, 0, 0);
}

// ---------------- fp32 -> bf16 convert (W1, W2) ----------------
__global__ __launch_bounds__(256) void k_convert(const float* __restrict__ src,
                                                 unsigned short* __restrict__ dst,
                                                 int n) {
  const int stride = gridDim.x * blockDim.x * 4;
  for (int i = (blockIdx.x * blockDim.x + threadIdx.x) * 4; i < n; i += stride) {
    float4 v = *reinterpret_cast<const float4*>(src + i);
    ushort4 o;
    o.x = f2bf(v.x); o.y = f2bf(v.y); o.z = f2bf(v.z); o.w = f2bf(v.w);
    *reinterpret_cast<ushort4*>(dst + i) = o;
  }
}

// ---------------- gumbel-softmax gating: split[15][4096], plus x -> bf16 ----------------
// block = one batch row b (4 waves); wave w handles nodes n = w, w+4, w+8, w+12.
// Coalesced mapping: lane l, chunk j -> element 4l + 256j (contiguous 1KB per wave instr).
// Valid because the reduction over d is permutation-invariant.
__global__ __launch_bounds__(256) void k_gate(
    const float* __restrict__ x, const float* __restrict__ gu,
    const float* __restrict__ fl, const float* __restrict__ thr,
    const float* __restrict__ fw, float* __restrict__ split,
    unsigned short* __restrict__ xb) {
  const int b = blockIdx.x;
  const int w = threadIdx.x >> 6, lane = threadIdx.x & 63;

  float xr[16];
  const float* xp = x + (size_t)b * DD;
  for (int j = 0; j < 4; ++j) {
    float4 v = *reinterpret_cast<const float4*>(xp + lane * 4 + j * 256);
    xr[j * 4 + 0] = v.x; xr[j * 4 + 1] = v.y;
    xr[j * 4 + 2] = v.z; xr[j * 4 + 3] = v.w;
  }
  if (w == 0) {  // side-effect: x -> bf16 (same mapping, contiguous stores)
    for (int j = 0; j < 4; ++j) {
      ushort4 o;
      o.x = f2bf(xr[j * 4 + 0]); o.y = f2bf(xr[j * 4 + 1]);
      o.z = f2bf(xr[j * 4 + 2]); o.w = f2bf(xr[j * 4 + 3]);
      *reinterpret_cast<ushort4*>(xb + (size_t)b * DD + lane * 4 + j * 256) = o;
    }
  }

  for (int n = w; n < NI; n += 4) {
    const float* gp = gu + ((size_t)n * BB + b) * DD;
    const float* fp = fl + (size_t)n * DD;
    const float* wp = fw + (size_t)n * DD;
    float num = 0.f, den = 0.f;
    for (int j = 0; j < 4; ++j) {
      const int e = lane * 4 + j * 256;
      float4 g4 = *reinterpret_cast<const float4*>(gp + e);
      float4 f4 = *reinterpret_cast<const float4*>(fp + e);
      float4 w4 = *reinterpret_cast<const float4*>(wp + e);
      float gv[4] = {g4.x, g4.y, g4.z, g4.w};
      float fv[4] = {f4.x, f4.y, f4.z, f4.w};
      float wv[4] = {w4.x, w4.y, w4.z, w4.w};
      for (int q = 0; q < 4; ++q) {
        float gg = -__logf(-__logf(gv[q] + 1e-10f) + 1e-10f);  // gumbel noise
        float e2 = __expf(fv[q] + gg);                         // tau = 1
        den += e2;
        num += xr[j * 4 + q] * wv[q] * e2;
      }
    }
    for (int off = 32; off; off >>= 1) {
      num += __shfl_xor(num, off);
      den += __shfl_xor(den, off);
    }
    if (lane == 0) {
      float agg = num / den;
      split[n * BB + b] = 1.f / (1.f + __expf(-(agg - thr[n])));
    }
  }
}

// ---------------- leaf routing probs: lp[4096][16] ----------------
__global__ __launch_bounds__(256) void k_leaf(const float* __restrict__ split,
                                              float* __restrict__ lp) {
  const int b = blockIdx.x * blockDim.x + threadIdx.x;
  if (b >= BB) return;
  float s[NI];
  for (int i = 0; i < NI; ++i) s[i] = split[i * BB + b];
  for (int leaf = 0; leaf < NL; ++leaf) {
    float p = 1.f;
    int node = 0;
    for (int lev = 0; lev < 4; ++lev) {
      int bit = (leaf >> (3 - lev)) & 1;
      p *= bit ? s[node] : (1.f - s[node]);
      node = 2 * node + 1 + bit;
    }
    lp[(size_t)b * NL + leaf] = p;
  }
}

// ---------------- GEMM1: Hs[l][b][h] = lp[b][l] * relu(x@W1[l]^T + b1[l]) in bf16
// 128x128 tile, BK=64, 4 waves (2x2 of 64x64), 16x16x32 bf16 MFMA (m97 structure)
__global__ __launch_bounds__(256) void k_gemm1(
    const unsigned short* __restrict__ xb, const unsigned short* __restrict__ w1b,
    const float* __restrict__ b1, const float* __restrict__ lp,
    unsigned short* __restrict__ hs) {
  __shared__ unsigned short lA[128 * 64];
  __shared__ unsigned short lB[128 * 64];
  __shared__ float s_lp[128];
  __shared__ float s_b1[128];

  const int tid = threadIdx.x;
  const int mt = blockIdx.x, nt = blockIdx.y, l = blockIdx.z;
  const int m0 = mt * 128, n0 = nt * 128;

  if (tid < 128) s_lp[tid] = lp[(size_t)(m0 + tid) * NL + l];
  else           s_b1[tid - 128] = b1[l * HH + n0 + (tid - 128)];

  const unsigned short* Ag = xb + (size_t)m0 * DD;
  const unsigned short* Bg = w1b + (size_t)l * HH * DD + (size_t)n0 * DD;

  f32x4 acc[4][4] = {};
  const int wv = tid >> 6, lane = tid & 63;
  const int wm = (wv & 1) * 64, wn = (wv >> 1) * 64;
  const int fr = lane & 15, fk = (lane >> 4) * 8;
  const int srow = tid >> 3, scol = (tid & 7) * 8;

  for (int k0 = 0; k0 < DD; k0 += 64) {
    for (int i = 0; i < 4; ++i)
      gld_lds16(Ag + (size_t)(srow + i * 32) * DD + k0 + scol,
                &lA[(srow + i * 32) * 64 + scol]);
    for (int i = 0; i < 4; ++i)
      gld_lds16(Bg + (size_t)(srow + i * 32) * DD + k0 + scol,
                &lB[(srow + i * 32) * 64 + scol]);
    __syncthreads();  // compiler drains vmcnt before s_barrier
    for (int kk = 0; kk < 64; kk += 32) {
      bf16x8 av[4], bv[4];
      for (int i = 0; i < 4; ++i)
        av[i] = *reinterpret_cast<const bf16x8*>(&lA[(wm + i * 16 + fr) * 64 + kk + fk]);
      for (int i = 0; i < 4; ++i)
        bv[i] = *reinterpret_cast<const bf16x8*>(&lB[(wn + i * 16 + fr) * 64 + kk + fk]);
      for (int mi = 0; mi < 4; ++mi)
        for (int ni = 0; ni < 4; ++ni)
          acc[mi][ni] = __builtin_amdgcn_mfma_f32_16x16x32_bf16(av[mi], bv[ni], acc[mi][ni], 0, 0, 0);
    }
    __syncthreads();
  }

  // C/D layout (m89-verified): col = lane&15, row = (lane>>4)*4 + reg
  const int cr = (lane >> 4) * 4, cc = lane & 15;
  for (int mi = 0; mi < 4; ++mi)
    for (int ni = 0; ni < 4; ++ni) {
      const int col = wn + ni * 16 + cc;
      const float bias = s_b1[col];
      for (int j = 0; j < 4; ++j) {
        const int row = wm + mi * 16 + cr + j;
        float v = acc[mi][ni][j] + bias;
        v = fmaxf(v, 0.f) * s_lp[row];
        hs[(size_t)l * BB * HH + (size_t)(m0 + row) * HH + (n0 + col)] = f2bf(v);
      }
    }
}

// ---------------- GEMM2: partial[kc][b][c] = sum over K-chunk of Hs*W2 (no atomics)
__global__ __launch_bounds__(256) void k_gemm2(
    const unsigned short* __restrict__ hs, const unsigned short* __restrict__ w2b,
    float* __restrict__ part) {
  __shared__ unsigned short lA[128 * 64];
  __shared__ unsigned short lB[128 * 64];

  const int tid = threadIdx.x;
  const int mt = blockIdx.x, kc = blockIdx.y;
  const int m0 = mt * 128;

  f32x4 acc[4][4] = {};
  const int wv = tid >> 6, lane = tid & 63;
  const int wm = (wv & 1) * 64, wn = (wv >> 1) * 64;
  const int fr = lane & 15, fk = (lane >> 4) * 8;
  const int srow = tid >> 3, scol = (tid & 7) * 8;

  for (int ks = 0; ks < 8; ++ks) {
    const int kg = kc * 512 + ks * 64;
    const int l = kg >> 8, h0 = kg & 255;  // BK=64 divides 256: one leaf per step
    const unsigned short* Ag = hs + (size_t)l * BB * HH + (size_t)m0 * HH + h0;
    for (int i = 0; i < 4; ++i)
      gld_lds16(Ag + (size_t)(srow + i * 32) * HH + scol,
                &lA[(srow + i * 32) * 64 + scol]);
    const unsigned short* Bg = w2b + (size_t)l * NC * HH + h0;
    for (int i = 0; i < 4; ++i) {
      const int c = srow + i * 32;
      u16x8 v = {};
      if (c < NC) v = *reinterpret_cast<const u16x8*>(Bg + (size_t)c * HH + scol);
      *reinterpret_cast<u16x8*>(&lB[c * 64 + scol]) = v;
    }
    __syncthreads();
    for (int kk = 0; kk < 64; kk += 32) {
      bf16x8 av[4], bv[4];
      for (int i = 0; i < 4; ++i)
        av[i] = *reinterpret_cast<const bf16x8*>(&lA[(wm + i * 16 + fr) * 64 + kk + fk]);
      for (int i = 0; i < 4; ++i)
        bv[i] = *reinterpret_cast<const bf16x8*>(&lB[(wn + i * 16 + fr) * 64 + kk + fk]);
      for (int mi = 0; mi < 4; ++mi)
        for (int ni = 0; ni < 4; ++ni)
          acc[mi][ni] = __builtin_amdgcn_mfma_f32_16x16x32_bf16(av[mi], bv[ni], acc[mi][ni], 0, 0, 0);
    }
    __syncthreads();
  }

  const int cr = (lane >> 4) * 4, cc = lane & 15;
  for (int mi = 0; mi < 4; ++mi)
    for (int ni = 0; ni < 4; ++ni) {
      const int col = wn + ni * 16 + cc;
      if (col < NC) {
        for (int j = 0; j < 4; ++j) {
          const int row = wm + mi * 16 + cr + j;
          part[((size_t)kc * BB + m0 + row) * NC + col] = acc[mi][ni][j];
        }
      }
    }
}

// ---------------- reduce partials + bias: out[b][c] = sum_kc part + sum_l lp*b2 ----------------
__global__ __launch_bounds__(256) void k_reduce(const float* __restrict__ part,
                                                const float* __restrict__ lp,
                                                const float* __restrict__ b2,
                                                float* __restrict__ out) {
  const int i = blockIdx.x * 256 + threadIdx.x;
  if (i >= BB * NC) return;
  const int b = i / NC, c = i - b * NC;
  float v = 0.f;
  for (int k = 0; k < 8; ++k) v += part[(size_t)k * BB * NC + i];
  const float* lpp = lp + (size_t)b * NL;
  for (int l = 0; l < NL; ++l) v += lpp[l] * b2[l * NC + c];
  out[i] = v;
}

// ---------------- launch ----------------
extern "C" void kernel_launch(void* const* d_in, const int* in_sizes, int n_in,
                              void* d_out, int out_size, void* d_ws, size_t ws_size,
                              hipStream_t stream) {
  const float* x   = (const float*)d_in[0];
  const float* gu  = (const float*)d_in[1];
  const float* fl  = (const float*)d_in[2];
  const float* thr = (const float*)d_in[3];
  const float* fw  = (const float*)d_in[4];
  const float* W1  = (const float*)d_in[5];
  const float* b1  = (const float*)d_in[6];
  const float* W2  = (const float*)d_in[7];
  const float* b2  = (const float*)d_in[8];
  float* out = (float*)d_out;

  char* ws = (char*)d_ws;
  // ws layout (bytes): total ~64.8 MB
  float* split          = (float*)(ws + 0);                 // 15*4096*4      = 245760
  float* lp             = (float*)(ws + 245760);            // 4096*16*4      = 262144
  unsigned short* xb    = (unsigned short*)(ws + 507904);   // 4096*1024*2    = 8388608
  unsigned short* w1b   = (unsigned short*)(ws + 8896512);  // 16*256*1024*2  = 8388608
  unsigned short* w2b   = (unsigned short*)(ws + 17285120); // 16*100*256*2   = 819200
  unsigned short* hsb   = (unsigned short*)(ws + 18104320); // 16*4096*256*2  = 33554432
  float* part           = (float*)(ws + 51658752);          // 8*4096*100*4   = 13107200

  k_gate<<<BB, 256, 0, stream>>>(x, gu, fl, thr, fw, split, xb);
  k_convert<<<2048, 256, 0, stream>>>(W1, w1b, NL * HH * DD);
  k_convert<<<512,  256, 0, stream>>>(W2, w2b, NL * NC * HH);
  k_leaf<<<16, 256, 0, stream>>>(split, lp);

  k_gemm1<<<dim3(32, 2, 16), 256, 0, stream>>>(xb, w1b, b1, lp, hsb);
  k_gemm2<<<dim3(32, 8, 1), 256, 0, stream>>>(hsb, w2b, part);
  k_reduce<<<1600, 256, 0, stream>>>(part, lp, b2, out);
}

// Round 3
// 459.060 us; speedup vs baseline: 1.2133x; 1.0292x over previous
//
#include <hip/hip_runtime.h>
#include <hip/hip_bf16.h>
#include <cstdint>
#include <cstddef>

#define NI 15
#define NL 16
#define DD 1024
#define NC 100
#define HH 256
#define BB 4096

typedef __attribute__((ext_vector_type(8))) short bf16x8;
typedef __attribute__((ext_vector_type(8))) unsigned short u16x8;
typedef __attribute__((ext_vector_type(4))) float f32x4;

__device__ __forceinline__ unsigned short f2bf(float f) {
  union { float f; unsigned u; } v; v.f = f;
  return (unsigned short)((v.u + 0x7FFFu + ((v.u >> 16) & 1u)) >> 16);
}

// async global->LDS, 16B per lane; LDS dest is wave-uniform base + lane*16
__device__ __forceinline__ void gld_lds16(const void* g, void* s) {
  __builtin_amdgcn_global_load_lds(
      (const __attribute__((address_space(1))) unsigned int*)g,
      (__attribute__((address_space(3))) unsigned int*)s, 16, 0, 0);
}

// ---------------- fp32 -> bf16 convert (W1 + W2 in one launch) ----------------
__global__ __launch_bounds__(256) void k_convertW(const float* __restrict__ W1,
                                                  const float* __restrict__ W2,
                                                  unsigned short* __restrict__ w1b,
                                                  unsigned short* __restrict__ w2b) {
  const int n1 = NL * HH * DD;           // 8388608 (div by 4)
  const int n2 = NL * NC * HH;           // 409600
  const int stride = gridDim.x * blockDim.x * 4;
  for (int i = (blockIdx.x * blockDim.x + threadIdx.x) * 4; i < n1 + n2; i += stride) {
    const float* s; unsigned short* d;
    if (i < n1) { s = W1 + i; d = w1b + i; }
    else        { s = W2 + (i - n1); d = w2b + (i - n1); }
    float4 v = *reinterpret_cast<const float4*>(s);
    ushort4 o;
    o.x = f2bf(v.x); o.y = f2bf(v.y); o.z = f2bf(v.z); o.w = f2bf(v.w);
    *reinterpret_cast<ushort4*>(d) = o;
  }
}

// ---------------- gumbel gating + leaf probs fused: lp[4096][16], plus x->bf16 ----------------
// block = one batch row b (4 waves); wave w handles nodes n = w, w+4, w+8, w+12.
// Coalesced: lane l, chunk j -> element 4l + 256j (permutation-invariant reduction).
__global__ __launch_bounds__(256) void k_gate(
    const float* __restrict__ x, const float* __restrict__ gu,
    const float* __restrict__ fl, const float* __restrict__ thr,
    const float* __restrict__ fw, float* __restrict__ lp,
    unsigned short* __restrict__ xb) {
  __shared__ float s_split[NI];
  const int b = blockIdx.x;
  const int w = threadIdx.x >> 6, lane = threadIdx.x & 63;

  float xr[16];
  const float* xp = x + (size_t)b * DD;
  for (int j = 0; j < 4; ++j) {
    float4 v = *reinterpret_cast<const float4*>(xp + lane * 4 + j * 256);
    xr[j * 4 + 0] = v.x; xr[j * 4 + 1] = v.y;
    xr[j * 4 + 2] = v.z; xr[j * 4 + 3] = v.w;
  }
  if (w == 0) {  // side-effect: x -> bf16 (contiguous stores)
    for (int j = 0; j < 4; ++j) {
      ushort4 o;
      o.x = f2bf(xr[j * 4 + 0]); o.y = f2bf(xr[j * 4 + 1]);
      o.z = f2bf(xr[j * 4 + 2]); o.w = f2bf(xr[j * 4 + 3]);
      *reinterpret_cast<ushort4*>(xb + (size_t)b * DD + lane * 4 + j * 256) = o;
    }
  }

  for (int n = w; n < NI; n += 4) {
    const float* gp = gu + ((size_t)n * BB + b) * DD;
    const float* fp = fl + (size_t)n * DD;
    const float* wp = fw + (size_t)n * DD;
    float num[4] = {0.f, 0.f, 0.f, 0.f}, den[4] = {0.f, 0.f, 0.f, 0.f};  // ILP
    for (int j = 0; j < 4; ++j) {
      const int e = lane * 4 + j * 256;
      float4 g4 = *reinterpret_cast<const float4*>(gp + e);
      float4 f4 = *reinterpret_cast<const float4*>(fp + e);
      float4 w4 = *reinterpret_cast<const float4*>(wp + e);
      float gv[4] = {g4.x, g4.y, g4.z, g4.w};
      float fv[4] = {f4.x, f4.y, f4.z, f4.w};
      float wv[4] = {w4.x, w4.y, w4.z, w4.w};
      for (int q = 0; q < 4; ++q) {
        float gg = -__logf(-__logf(gv[q] + 1e-10f) + 1e-10f);  // gumbel noise
        float e2 = __expf(fv[q] + gg);                         // tau = 1
        den[j] += e2;
        num[j] += xr[j * 4 + q] * wv[q] * e2;
      }
    }
    float nums = (num[0] + num[1]) + (num[2] + num[3]);
    float dens = (den[0] + den[1]) + (den[2] + den[3]);
    for (int off = 32; off; off >>= 1) {
      nums += __shfl_xor(nums, off);
      dens += __shfl_xor(dens, off);
    }
    if (lane == 0) {
      float agg = nums / dens;
      s_split[n] = 1.f / (1.f + __expf(-(agg - thr[n])));
    }
  }
  __syncthreads();
  if (threadIdx.x < NL) {  // fused leaf-prob: 16 threads, one leaf each
    const int leaf = threadIdx.x;
    float p = 1.f; int node = 0;
    for (int lev = 0; lev < 4; ++lev) {
      int bit = (leaf >> (3 - lev)) & 1;
      float s = s_split[node];
      p *= bit ? s : (1.f - s);
      node = 2 * node + 1 + bit;
    }
    lp[(size_t)b * NL + leaf] = p;
  }
}

// ---------------- GEMM1 (pipelined): Hs[l][b][h] = lp[b][l]*relu(x@W1[l]^T + b1[l]), bf16
// 256x256 tile, BK=32, triple-buffered LDS, counted vmcnt(8) (T3+T4), setprio (T5).
// 8 waves = 2M x 4N; per-wave 128x64 output; 1 block/CU (96KB LDS), grid 16(l) x 16(mt).
// BK=32 => 64B LDS rows: fragment reads alternate bank halves -> no swizzle needed.
__global__ __launch_bounds__(512, 2) void k_gemm1(
    const unsigned short* __restrict__ xb, const unsigned short* __restrict__ w1b,
    const float* __restrict__ b1, const float* __restrict__ lp,
    unsigned short* __restrict__ hs) {
  __shared__ unsigned short lA[3][256 * 32];
  __shared__ unsigned short lB[3][256 * 32];
  __shared__ float s_lp[256];
  __shared__ float s_b1[256];

  const int tid = threadIdx.x;
  const int l = blockIdx.x, mt = blockIdx.y;
  const int m0 = mt * 256;

  if (tid < 256) s_lp[tid] = lp[(size_t)(m0 + tid) * NL + l];
  else           s_b1[tid & 255] = b1[l * HH + (tid & 255)];

  const unsigned short* Ag = xb  + (size_t)m0 * DD;
  const unsigned short* Bg = w1b + (size_t)l * HH * DD;

  const int srow = tid >> 2;        // 0..127
  const int scol = (tid & 3) * 8;   // elem offset in row

  __syncthreads();  // s_lp/s_b1 visible; vmcnt clean before pipeline

#define STAGE1(tt, bb) do {                                                       \
    const int kk_ = (tt) * 32;                                                    \
    gld_lds16(Ag + (size_t)srow * DD + kk_ + scol,         &lA[bb][srow * 32 + scol]);         \
    gld_lds16(Ag + (size_t)(srow + 128) * DD + kk_ + scol, &lA[bb][(srow + 128) * 32 + scol]); \
    gld_lds16(Bg + (size_t)srow * DD + kk_ + scol,         &lB[bb][srow * 32 + scol]);         \
    gld_lds16(Bg + (size_t)(srow + 128) * DD + kk_ + scol, &lB[bb][(srow + 128) * 32 + scol]); \
  } while (0)

  STAGE1(0, 0); STAGE1(1, 1); STAGE1(2, 2);  // 12 loads in flight

  const int wid = tid >> 6, lane = tid & 63;
  const int wr = wid >> 2, wc = wid & 3;
  const int g8 = (lane >> 4) * 8, fr = lane & 15;

  f32x4 acc[8][4] = {};

  int bufi = 0;
  for (int t = 0; t < 32; ++t) {
    const int rem = 31 - t;
    // tile t's 4 loads are older than the (<=8) outstanding from stages t+1,t+2
    if (rem >= 2)      { asm volatile("s_waitcnt vmcnt(8)" ::: "memory"); }
    else if (rem == 1) { asm volatile("s_waitcnt vmcnt(4)" ::: "memory"); }
    else               { asm volatile("s_waitcnt vmcnt(0)" ::: "memory"); }
    __builtin_amdgcn_s_barrier();
    __builtin_amdgcn_sched_barrier(0);

    const unsigned short* bA = lA[bufi];
    const unsigned short* bB = lB[bufi];
    bf16x8 av[8], bv[4];
#pragma unroll
    for (int mi = 0; mi < 8; ++mi)
      av[mi] = *reinterpret_cast<const bf16x8*>(&bA[(wr * 128 + mi * 16 + fr) * 32 + g8]);
#pragma unroll
    for (int nj = 0; nj < 4; ++nj)
      bv[nj] = *reinterpret_cast<const bf16x8*>(&bB[(wc * 64 + nj * 16 + fr) * 32 + g8]);

    __builtin_amdgcn_s_setprio(1);
#pragma unroll
    for (int mi = 0; mi < 8; ++mi)
#pragma unroll
      for (int nj = 0; nj < 4; ++nj)
        acc[mi][nj] = __builtin_amdgcn_mfma_f32_16x16x32_bf16(av[mi], bv[nj], acc[mi][nj], 0, 0, 0);
    __builtin_amdgcn_s_setprio(0);

    __builtin_amdgcn_sched_barrier(0);
    __builtin_amdgcn_s_barrier();       // all waves done reading buf[bufi]
    __builtin_amdgcn_sched_barrier(0);
    if (t + 3 < 32) STAGE1(t + 3, bufi);  // overwrite just-consumed buffer
    bufi = (bufi == 2) ? 0 : bufi + 1;
  }
#undef STAGE1

  // C/D layout (m89-verified): col = lane&15, row = (lane>>4)*4 + reg
  const int cr = (lane >> 4) * 4, cc = lane & 15;
  unsigned short* Hp = hs + (size_t)l * BB * HH;
#pragma unroll
  for (int mi = 0; mi < 8; ++mi)
#pragma unroll
    for (int nj = 0; nj < 4; ++nj) {
      const int col = wc * 64 + nj * 16 + cc;
      const float bias = s_b1[col];
#pragma unroll
      for (int j = 0; j < 4; ++j) {
        const int row = wr * 128 + mi * 16 + cr + j;
        float v = acc[mi][nj][j] + bias;
        v = fmaxf(v, 0.f) * s_lp[row];
        Hp[(size_t)(m0 + row) * HH + col] = f2bf(v);
      }
    }
}

// ---------------- GEMM2: partial[kc][b][c] = sum over K-chunk of Hs*W2 ----------------
__global__ __launch_bounds__(256) void k_gemm2(
    const unsigned short* __restrict__ hs, const unsigned short* __restrict__ w2b,
    float* __restrict__ part) {
  __shared__ unsigned short lA[128 * 64];
  __shared__ unsigned short lB[128 * 64];

  const int tid = threadIdx.x;
  const int mt = blockIdx.x, kc = blockIdx.y;
  const int m0 = mt * 128;

  f32x4 acc[4][4] = {};
  const int wv = tid >> 6, lane = tid & 63;
  const int wm = (wv & 1) * 64, wn = (wv >> 1) * 64;
  const int fr = lane & 15, fk = (lane >> 4) * 8;
  const int srow = tid >> 3, scol = (tid & 7) * 8;

  for (int ks = 0; ks < 8; ++ks) {
    const int kg = kc * 512 + ks * 64;
    const int l = kg >> 8, h0 = kg & 255;
    const unsigned short* Ag = hs + (size_t)l * BB * HH + (size_t)m0 * HH + h0;
    for (int i = 0; i < 4; ++i)
      gld_lds16(Ag + (size_t)(srow + i * 32) * HH + scol,
                &lA[(srow + i * 32) * 64 + scol]);
    const unsigned short* Bg = w2b + (size_t)l * NC * HH + h0;
    for (int i = 0; i < 4; ++i) {
      const int c = srow + i * 32;
      u16x8 v = {};
      if (c < NC) v = *reinterpret_cast<const u16x8*>(Bg + (size_t)c * HH + scol);
      *reinterpret_cast<u16x8*>(&lB[c * 64 + scol]) = v;
    }
    __syncthreads();
    for (int kk = 0; kk < 64; kk += 32) {
      bf16x8 av[4], bv[4];
      for (int i = 0; i < 4; ++i)
        av[i] = *reinterpret_cast<const bf16x8*>(&lA[(wm + i * 16 + fr) * 64 + kk + fk]);
      for (int i = 0; i < 4; ++i)
        bv[i] = *reinterpret_cast<const bf16x8*>(&lB[(wn + i * 16 + fr) * 64 + kk + fk]);
      for (int mi = 0; mi < 4; ++mi)
        for (int ni = 0; ni < 4; ++ni)
          acc[mi][ni] = __builtin_amdgcn_mfma_f32_16x16x32_bf16(av[mi], bv[ni], acc[mi][ni], 0, 0, 0);
    }
    __syncthreads();
  }

  const int cr = (lane >> 4) * 4, cc = lane & 15;
  for (int mi = 0; mi < 4; ++mi)
    for (int ni = 0; ni < 4; ++ni) {
      const int col = wn + ni * 16 + cc;
      if (col < NC) {
        for (int j = 0; j < 4; ++j) {
          const int row = wm + mi * 16 + cr + j;
          part[((size_t)kc * BB + m0 + row) * NC + col] = acc[mi][ni][j];
        }
      }
    }
}

// ---------------- reduce partials + bias ----------------
__global__ __launch_bounds__(256) void k_reduce(const float* __restrict__ part,
                                                const float* __restrict__ lp,
                                                const float* __restrict__ b2,
                                                float* __restrict__ out) {
  const int i = blockIdx.x * 256 + threadIdx.x;
  if (i >= BB * NC) return;
  const int b = i / NC, c = i - b * NC;
  float v = 0.f;
  for (int k = 0; k < 8; ++k) v += part[(size_t)k * BB * NC + i];
  const float* lpp = lp + (size_t)b * NL;
  for (int l = 0; l < NL; ++l) v += lpp[l] * b2[l * NC + c];
  out[i] = v;
}

// ---------------- launch ----------------
extern "C" void kernel_launch(void* const* d_in, const int* in_sizes, int n_in,
                              void* d_out, int out_size, void* d_ws, size_t ws_size,
                              hipStream_t stream) {
  const float* x   = (const float*)d_in[0];
  const float* gu  = (const float*)d_in[1];
  const float* fl  = (const float*)d_in[2];
  const float* thr = (const float*)d_in[3];
  const float* fw  = (const float*)d_in[4];
  const float* W1  = (const float*)d_in[5];
  const float* b1  = (const float*)d_in[6];
  const float* W2  = (const float*)d_in[7];
  const float* b2  = (const float*)d_in[8];
  float* out = (float*)d_out;

  char* ws = (char*)d_ws;
  // ws layout (bytes): total ~64.5 MB
  float* lp             = (float*)(ws + 0);                 // 4096*16*4      = 262144
  unsigned short* xb    = (unsigned short*)(ws + 262144);   // 4096*1024*2    = 8388608
  unsigned short* w1b   = (unsigned short*)(ws + 8650752);  // 16*256*1024*2  = 8388608
  unsigned short* w2b   = (unsigned short*)(ws + 17039360); // 16*100*256*2   = 819200
  unsigned short* hsb   = (unsigned short*)(ws + 17858560); // 16*4096*256*2  = 33554432
  float* part           = (float*)(ws + 51412992);          // 8*4096*100*4   = 13107200

  k_gate<<<BB, 256, 0, stream>>>(x, gu, fl, thr, fw, lp, xb);
  k_convertW<<<2048, 256, 0, stream>>>(W1, W2, w1b, w2b);

  k_gemm1<<<dim3(16, 16), 512, 0, stream>>>(xb, w1b, b1, lp, hsb);
  k_gemm2<<<dim3(32, 8), 256, 0, stream>>>(hsb, w2b, part);
  k_reduce<<<1600, 256, 0, stream>>>(part, lp, b2, out);
}

// Round 6
// 454.617 us; speedup vs baseline: 1.2252x; 1.0098x over previous
//
#include <hip/hip_runtime.h>
#include <hip/hip_bf16.h>
#include <cstdint>
#include <cstddef>

#define NI 15
#define NL 16
#define DD 1024
#define NC 100
#define HH 256
#define BB 4096

typedef __attribute__((ext_vector_type(8))) short bf16x8;
typedef __attribute__((ext_vector_type(8))) unsigned short u16x8;
typedef __attribute__((ext_vector_type(4))) float f32x4;

__device__ __forceinline__ unsigned short f2bf(float f) {
  union { float f; unsigned u; } v; v.f = f;
  return (unsigned short)((v.u + 0x7FFFu + ((v.u >> 16) & 1u)) >> 16);
}

// async global->LDS, 16B per lane; LDS dest is wave-uniform base + lane*16
__device__ __forceinline__ void gld_lds16(const void* g, void* s) {
  __builtin_amdgcn_global_load_lds(
      (const __attribute__((address_space(1))) unsigned int*)g,
      (__attribute__((address_space(3))) unsigned int*)s, 16, 0, 0);
}

// ---------------- fp32 -> bf16 convert (W1 + W2 in one launch) ----------------
__global__ __launch_bounds__(256) void k_convertW(const float* __restrict__ W1,
                                                  const float* __restrict__ W2,
                                                  unsigned short* __restrict__ w1b,
                                                  unsigned short* __restrict__ w2b) {
  const int n1 = NL * HH * DD;           // 8388608 (div by 4)
  const int n2 = NL * NC * HH;           // 409600
  const int stride = gridDim.x * blockDim.x * 4;
  for (int i = (blockIdx.x * blockDim.x + threadIdx.x) * 4; i < n1 + n2; i += stride) {
    const float* s; unsigned short* d;
    if (i < n1) { s = W1 + i; d = w1b + i; }
    else        { s = W2 + (i - n1); d = w2b + (i - n1); }
    float4 v = *reinterpret_cast<const float4*>(s);
    ushort4 o;
    o.x = f2bf(v.x); o.y = f2bf(v.y); o.z = f2bf(v.z); o.w = f2bf(v.w);
    *reinterpret_cast<ushort4*>(d) = o;
  }
}

// ---------------- gumbel gating + leaf probs fused: lp[4096][16], plus x->bf16 ----------------
__global__ __launch_bounds__(256) void k_gate(
    const float* __restrict__ x, const float* __restrict__ gu,
    const float* __restrict__ fl, const float* __restrict__ thr,
    const float* __restrict__ fw, float* __restrict__ lp,
    unsigned short* __restrict__ xb) {
  __shared__ float s_split[NI];
  const int b = blockIdx.x;
  const int w = threadIdx.x >> 6, lane = threadIdx.x & 63;

  float xr[16];
  const float* xp = x + (size_t)b * DD;
  for (int j = 0; j < 4; ++j) {
    float4 v = *reinterpret_cast<const float4*>(xp + lane * 4 + j * 256);
    xr[j * 4 + 0] = v.x; xr[j * 4 + 1] = v.y;
    xr[j * 4 + 2] = v.z; xr[j * 4 + 3] = v.w;
  }
  if (w == 0) {  // side-effect: x -> bf16 (contiguous stores)
    for (int j = 0; j < 4; ++j) {
      ushort4 o;
      o.x = f2bf(xr[j * 4 + 0]); o.y = f2bf(xr[j * 4 + 1]);
      o.z = f2bf(xr[j * 4 + 2]); o.w = f2bf(xr[j * 4 + 3]);
      *reinterpret_cast<ushort4*>(xb + (size_t)b * DD + lane * 4 + j * 256) = o;
    }
  }

  for (int n = w; n < NI; n += 4) {
    const float* gp = gu + ((size_t)n * BB + b) * DD;
    const float* fp = fl + (size_t)n * DD;
    const float* wp = fw + (size_t)n * DD;
    float num[4] = {0.f, 0.f, 0.f, 0.f}, den[4] = {0.f, 0.f, 0.f, 0.f};  // ILP
    for (int j = 0; j < 4; ++j) {
      const int e = lane * 4 + j * 256;
      float4 g4 = *reinterpret_cast<const float4*>(gp + e);
      float4 f4 = *reinterpret_cast<const float4*>(fp + e);
      float4 w4 = *reinterpret_cast<const float4*>(wp + e);
      float gv[4] = {g4.x, g4.y, g4.z, g4.w};
      float fv[4] = {f4.x, f4.y, f4.z, f4.w};
      float wv[4] = {w4.x, w4.y, w4.z, w4.w};
      for (int q = 0; q < 4; ++q) {
        float gg = -__logf(-__logf(gv[q] + 1e-10f) + 1e-10f);  // gumbel noise
        float e2 = __expf(fv[q] + gg);                         // tau = 1
        den[j] += e2;
        num[j] += xr[j * 4 + q] * wv[q] * e2;
      }
    }
    float nums = (num[0] + num[1]) + (num[2] + num[3]);
    float dens = (den[0] + den[1]) + (den[2] + den[3]);
    for (int off = 32; off; off >>= 1) {
      nums += __shfl_xor(nums, off);
      dens += __shfl_xor(dens, off);
    }
    if (lane == 0) {
      float agg = nums / dens;
      s_split[n] = 1.f / (1.f + __expf(-(agg - thr[n])));
    }
  }
  __syncthreads();
  if (threadIdx.x < NL) {  // fused leaf-prob: 16 threads, one leaf each
    const int leaf = threadIdx.x;
    float p = 1.f; int node = 0;
    for (int lev = 0; lev < 4; ++lev) {
      int bit = (leaf >> (3 - lev)) & 1;
      float s = s_split[node];
      p *= bit ? s : (1.f - s);
      node = 2 * node + 1 + bit;
    }
    lp[(size_t)b * NL + leaf] = p;
  }
}

// ---------------- GEMM1 (pipelined + swizzled): Hs[l][b][h] = lp*relu(x@W1[l]^T + b1[l])
// 256x256 tile, BK=32, triple-buffer, counted vmcnt (T3+T4), setprio (T5), T2 swizzle.
// Swizzle: 64B rows have 4x16B slots; slot ^= (row>>1)&3 spreads 8 consecutive rows
// across all 8 (parity x slot) bank groups -> 2-way (free). Applied to BOTH the
// global source column (LDS stays lane-linear per gld_lds16 HW) and the frag reads.
__global__ __launch_bounds__(512, 2) void k_gemm1(
    const unsigned short* __restrict__ xb, const unsigned short* __restrict__ w1b,
    const float* __restrict__ b1, const float* __restrict__ lp,
    unsigned short* __restrict__ hs) {
  __shared__ unsigned short lA[3][256 * 32];
  __shared__ unsigned short lB[3][256 * 32];
  __shared__ float s_lp[256];
  __shared__ float s_b1[256];

  const int tid = threadIdx.x;
  const int l = blockIdx.x, mt = blockIdx.y;
  const int m0 = mt * 256;

  if (tid < 256) s_lp[tid] = lp[(size_t)(m0 + tid) * NL + l];
  else           s_b1[tid & 255] = b1[l * HH + (tid & 255)];

  const unsigned short* Ag = xb  + (size_t)m0 * DD;
  const unsigned short* Bg = w1b + (size_t)l * HH * DD;

  const int srow = tid >> 2;                                  // 0..127
  const int sslot = tid & 3;                                  // 16B slot in 64B row
  const int scol = (sslot ^ ((srow >> 1) & 3)) * 8;           // swizzled SOURCE col (elems)
  const int dcol = sslot * 8;                                 // linear LDS col

  __syncthreads();  // s_lp/s_b1 visible; vmcnt clean before pipeline

#define STAGE1(tt, bb) do {                                                                    \
    const int kk_ = (tt) * 32;                                                                 \
    gld_lds16(Ag + (size_t)srow * DD + kk_ + scol,         &lA[bb][srow * 32 + dcol]);         \
    gld_lds16(Ag + (size_t)(srow + 128) * DD + kk_ + scol, &lA[bb][(srow + 128) * 32 + dcol]); \
    gld_lds16(Bg + (size_t)srow * DD + kk_ + scol,         &lB[bb][srow * 32 + dcol]);         \
    gld_lds16(Bg + (size_t)(srow + 128) * DD + kk_ + scol, &lB[bb][(srow + 128) * 32 + dcol]); \
  } while (0)

  STAGE1(0, 0); STAGE1(1, 1); STAGE1(2, 2);  // 12 loads in flight

  const int wid = tid >> 6, lane = tid & 63;
  const int wr = wid >> 2, wc = wid & 3;
  const int fr = lane & 15;
  // swizzled frag col: slot = lane>>4, f(row) = (fr>>1)&3 (row = 16k + fr)
  const int fcol = (((lane >> 4) ^ ((fr >> 1) & 3))) * 8;

  f32x4 acc[8][4] = {};

  int bufi = 0;
  for (int t = 0; t < 32; ++t) {
    const int rem = 31 - t;
    if (rem >= 2)      { asm volatile("s_waitcnt vmcnt(8)" ::: "memory"); }
    else if (rem == 1) { asm volatile("s_waitcnt vmcnt(4)" ::: "memory"); }
    else               { asm volatile("s_waitcnt vmcnt(0)" ::: "memory"); }
    __builtin_amdgcn_s_barrier();
    __builtin_amdgcn_sched_barrier(0);

    const unsigned short* bA = lA[bufi];
    const unsigned short* bB = lB[bufi];
    bf16x8 av[8], bv[4];
#pragma unroll
    for (int mi = 0; mi < 8; ++mi)
      av[mi] = *reinterpret_cast<const bf16x8*>(&bA[(wr * 128 + mi * 16 + fr) * 32 + fcol]);
#pragma unroll
    for (int nj = 0; nj < 4; ++nj)
      bv[nj] = *reinterpret_cast<const bf16x8*>(&bB[(wc * 64 + nj * 16 + fr) * 32 + fcol]);

    __builtin_amdgcn_s_setprio(1);
#pragma unroll
    for (int mi = 0; mi < 8; ++mi)
#pragma unroll
      for (int nj = 0; nj < 4; ++nj)
        acc[mi][nj] = __builtin_amdgcn_mfma_f32_16x16x32_bf16(av[mi], bv[nj], acc[mi][nj], 0, 0, 0);
    __builtin_amdgcn_s_setprio(0);

    __builtin_amdgcn_sched_barrier(0);
    __builtin_amdgcn_s_barrier();       // all waves done reading buf[bufi]
    __builtin_amdgcn_sched_barrier(0);
    if (t + 3 < 32) STAGE1(t + 3, bufi);
    bufi = (bufi == 2) ? 0 : bufi + 1;
  }
#undef STAGE1

  // C/D layout (m89-verified): col = lane&15, row = (lane>>4)*4 + reg
  const int cr = (lane >> 4) * 4, cc = lane & 15;
  unsigned short* Hp = hs + (size_t)l * BB * HH;
#pragma unroll
  for (int mi = 0; mi < 8; ++mi)
#pragma unroll
    for (int nj = 0; nj < 4; ++nj) {
      const int col = wc * 64 + nj * 16 + cc;
      const float bias = s_b1[col];
#pragma unroll
      for (int j = 0; j < 4; ++j) {
        const int row = wr * 128 + mi * 16 + cr + j;
        float v = acc[mi][nj][j] + bias;
        v = fmaxf(v, 0.f) * s_lp[row];
        Hp[(size_t)(m0 + row) * HH + col] = f2bf(v);
      }
    }
}

// ---------------- GEMM2 (swizzled): partial[kc][b][c] = K-chunk of Hs*W2 ----------------
// 128B rows (BK=64) -> 8 slots; slot ^= row&7 -> conflict-free frag reads.
__global__ __launch_bounds__(256) void k_gemm2(
    const unsigned short* __restrict__ hs, const unsigned short* __restrict__ w2b,
    float* __restrict__ part) {
  __shared__ unsigned short lA[128 * 64];
  __shared__ unsigned short lB[128 * 64];

  const int tid = threadIdx.x;
  const int mt = blockIdx.x, kc = blockIdx.y;
  const int m0 = mt * 128;

  f32x4 acc[4][4] = {};
  const int wv = tid >> 6, lane = tid & 63;
  const int wm = (wv & 1) * 64, wn = (wv >> 1) * 64;
  const int fr = lane & 15, fk = (lane >> 4) * 8;
  const int srow = tid >> 3;                               // 0..31
  const int sslot = tid & 7;                               // 16B slot in 128B row
  const int scol = (sslot ^ (srow & 7)) * 8;               // swizzled source col
  const int dcol = sslot * 8;                              // linear LDS col

  for (int ks = 0; ks < 8; ++ks) {
    const int kg = kc * 512 + ks * 64;
    const int l = kg >> 8, h0 = kg & 255;
    const unsigned short* Ag = hs + (size_t)l * BB * HH + (size_t)m0 * HH + h0;
    for (int i = 0; i < 4; ++i)  // rows srow+i*32: (row&7)==(srow&7), same swizzle
      gld_lds16(Ag + (size_t)(srow + i * 32) * HH + scol,
                &lA[(srow + i * 32) * 64 + dcol]);
    const unsigned short* Bg = w2b + (size_t)l * NC * HH + h0;
    for (int i = 0; i < 4; ++i) {
      const int c = srow + i * 32;
      u16x8 v = {};
      if (c < NC) v = *reinterpret_cast<const u16x8*>(Bg + (size_t)c * HH + dcol);
      *reinterpret_cast<u16x8*>(&lB[c * 64 + (dcol ^ ((c & 7) * 8))]) = v;
    }
    __syncthreads();
    for (int kk = 0; kk < 64; kk += 32) {
      const int fcol = (((kk + fk) >> 3) ^ (fr & 7)) * 8;  // swizzled frag col
      bf16x8 av[4], bv[4];
      for (int i = 0; i < 4; ++i)
        av[i] = *reinterpret_cast<const bf16x8*>(&lA[(wm + i * 16 + fr) * 64 + fcol]);
      for (int i = 0; i < 4; ++i)
        bv[i] = *reinterpret_cast<const bf16x8*>(&lB[(wn + i * 16 + fr) * 64 + fcol]);
      for (int mi = 0; mi < 4; ++mi)
        for (int ni = 0; ni < 4; ++ni)
          acc[mi][ni] = __builtin_amdgcn_mfma_f32_16x16x32_bf16(av[mi], bv[ni], acc[mi][ni], 0, 0, 0);
    }
    __syncthreads();
  }

  const int cr = (lane >> 4) * 4, cc = lane & 15;
  for (int mi = 0; mi < 4; ++mi)
    for (int ni = 0; ni < 4; ++ni) {
      const int col = wn + ni * 16 + cc;
      if (col < NC) {
        for (int j = 0; j < 4; ++j) {
          const int row = wm + mi * 16 + cr + j;
          part[((size_t)kc * BB + m0 + row) * NC + col] = acc[mi][ni][j];
        }
      }
    }
}

// ---------------- reduce partials + bias ----------------
__global__ __launch_bounds__(256) void k_reduce(const float* __restrict__ part,
                                                const float* __restrict__ lp,
                                                const float* __restrict__ b2,
                                                float* __restrict__ out) {
  const int i = blockIdx.x * 256 + threadIdx.x;
  if (i >= BB * NC) return;
  const int b = i / NC, c = i - b * NC;
  float v = 0.f;
  for (int k = 0; k < 8; ++k) v += part[(size_t)k * BB * NC + i];
  const float* lpp = lp + (size_t)b * NL;
  for (int l = 0; l < NL; ++l) v += lpp[l] * b2[l * NC + c];
  out[i] = v;
}

// ---------------- launch ----------------
extern "C" void kernel_launch(void* const* d_in, const int* in_sizes, int n_in,
                              void* d_out, int out_size, void* d_ws, size_t ws_size,
                              hipStream_t stream) {
  const float* x   = (const float*)d_in[0];
  const float* gu  = (const float*)d_in[1];
  const float* fl  = (const float*)d_in[2];
  const float* thr = (const float*)d_in[3];
  const float* fw  = (const float*)d_in[4];
  const float* W1  = (const float*)d_in[5];
  const float* b1  = (const float*)d_in[6];
  const float* W2  = (const float*)d_in[7];
  const float* b2  = (const float*)d_in[8];
  float* out = (float*)d_out;

  char* ws = (char*)d_ws;
  float* lp             = (float*)(ws + 0);                 // 4096*16*4      = 262144
  unsigned short* xb    = (unsigned short*)(ws + 262144);   // 4096*1024*2    = 8388608
  unsigned short* w1b   = (unsigned short*)(ws + 8650752);  // 16*256*1024*2  = 8388608
  unsigned short* w2b   = (unsigned short*)(ws + 17039360); // 16*100*256*2   = 819200
  unsigned short* hsb   = (unsigned short*)(ws + 17858560); // 16*4096*256*2  = 33554432
  float* part           = (float*)(ws + 51412992);          // 8*4096*100*4   = 13107200

  k_gate<<<BB, 256, 0, stream>>>(x, gu, fl, thr, fw, lp, xb);
  k_convertW<<<2048, 256, 0, stream>>>(W1, W2, w1b, w2b);

  k_gemm1<<<dim3(16, 16), 512, 0, stream>>>(xb, w1b, b1, lp, hsb);
  k_gemm2<<<dim3(32, 8), 256, 0, stream>>>(hsb, w2b, part);
  k_reduce<<<1600, 256, 0, stream>>>(part, lp, b2, out);
}